// Round 1
// 647.433 us; speedup vs baseline: 1.2038x; 1.2038x over previous
//
#include <hip/hip_runtime.h>
#include <hip/hip_fp16.h>
#include <cstdint>
#include <cstddef>

#define N_NODES   262144
#define NG        256
#define PP        1024
#define NE        4194304
#define FIN       128
#define HH        32
#define NC        10
#define OL        16
#define IL        96
#define NITER     3
#define ECHUNK    4096
#define NCHUNK    (NE/ECHUNK)   // 1024
#define ECAP      18432
#define HSTR      36            // padded LDS row stride (floats): quad-bank group of row k = k mod 8

typedef _Float16 half8 __attribute__((ext_vector_type(8)));
typedef float f32x4 __attribute__((ext_vector_type(4)));

// ---------------- per-chunk per-graph edge histogram (transposed output) ----------------
__global__ void k_hist(const int* __restrict__ ei, unsigned* __restrict__ histT) {
  __shared__ unsigned lh[NG];
  int t = threadIdx.x, b = blockIdx.x;
  lh[t] = 0;
  __syncthreads();
  int base = b * ECHUNK;
  for (int q = t; q < ECHUNK; q += 256) {
    int e = base + q;
    int s = ei[e], d = ei[NE + e];
    if (s != d) atomicAdd(&lh[s >> 10], 1u);
  }
  __syncthreads();
  histT[t * NCHUNK + b] = lh[t];   // [g][ch]
}

// ---------------- per-graph scan over chunks: cbaseT[ch][g] (within-graph excl), gtot[g] ---
__global__ void k_scanA(const unsigned* __restrict__ histT, unsigned* __restrict__ cbaseT,
                        unsigned* __restrict__ gtot) {
  __shared__ unsigned wtot[4];
  int t = threadIdx.x, g = blockIdx.x;
  int lane = t & 63, wv = t >> 6;
  uint4 hv = *(const uint4*)(histT + (size_t)g * NCHUNK + t * 4);
  unsigned s0 = hv.x, s1 = s0 + hv.y, s2 = s1 + hv.z, s3 = s2 + hv.w;
  unsigned tsum = s3, sc = tsum;
  for (int d = 1; d < 64; d <<= 1) {
    unsigned v = __shfl_up(sc, d, 64);
    if (lane >= d) sc += v;
  }
  if (lane == 63) wtot[wv] = sc;
  __syncthreads();
  unsigned woff = 0;
  for (int w = 0; w < wv; ++w) woff += wtot[w];
  unsigned base = woff + sc - tsum;   // exclusive
  cbaseT[(size_t)(t * 4 + 0) * NG + g] = base;
  cbaseT[(size_t)(t * 4 + 1) * NG + g] = base + s0;
  cbaseT[(size_t)(t * 4 + 2) * NG + g] = base + s1;
  cbaseT[(size_t)(t * 4 + 3) * NG + g] = base + s2;
  if (t == 255) gtot[g] = woff + sc;
}

// ---------------- scan of per-graph totals -> gbase[257] ----------------
__global__ void k_scanB(const unsigned* __restrict__ gtot, unsigned* __restrict__ gbase) {
  __shared__ unsigned wtot[4];
  int t = threadIdx.x;
  int lane = t & 63, wv = t >> 6;
  unsigned x = gtot[t], sc = x;
  for (int d = 1; d < 64; d <<= 1) {
    unsigned v = __shfl_up(sc, d, 64);
    if (lane >= d) sc += v;
  }
  if (lane == 63) wtot[wv] = sc;
  __syncthreads();
  unsigned woff = 0;
  for (int w = 0; w < wv; ++w) woff += wtot[w];
  gbase[t] = woff + sc - x;
  if (t == 255) gbase[256] = woff + sc;
}

// ---------------- scatter edges into graph buckets ----------------
__global__ void k_scatter(const int* __restrict__ ei, const unsigned* __restrict__ cbaseT,
                          const unsigned* __restrict__ gbase, unsigned* __restrict__ epack) {
  __shared__ unsigned lcur[NG];
  int t = threadIdx.x, b = blockIdx.x;
  lcur[t] = gbase[t] + cbaseT[(size_t)b * NG + t];
  __syncthreads();
  int base = b * ECHUNK;
  for (int q = t; q < ECHUNK; q += 256) {
    int e = base + q;
    int s = ei[e], d = ei[NE + e];
    if (s != d) {
      int g = s >> 10;
      unsigned pos = atomicAdd(&lcur[g], 1u);
      epack[pos] = (unsigned)(s & 1023) | ((unsigned)(d & 1023) << 10);
    }
  }
}

// ---------------- per-graph counting sort by dst offset -> CSR + u16 src list ------------
__global__ __launch_bounds__(256) void k_dstsort(const unsigned* __restrict__ epack,
                          const unsigned* __restrict__ gbase,
                          unsigned short* __restrict__ esrc16,
                          unsigned* __restrict__ dstptr) {
  __shared__ unsigned shist[PP];
  __shared__ unsigned wsum[256];
  __shared__ unsigned cur[PP];
  int t = threadIdx.x, g = blockIdx.x;
  unsigned e0 = gbase[g], e1 = gbase[g + 1];
  for (int i = t; i < PP; i += 256) shist[i] = 0;
  __syncthreads();
  for (unsigned e = e0 + t; e < e1; e += 256)
    atomicAdd(&shist[(epack[e] >> 10) & 1023], 1u);
  __syncthreads();
  unsigned h0 = shist[4 * t], h1 = shist[4 * t + 1], h2 = shist[4 * t + 2], h3 = shist[4 * t + 3];
  unsigned tsum = h0 + h1 + h2 + h3;
  wsum[t] = tsum;
  __syncthreads();
  for (int off = 1; off < 256; off <<= 1) {
    unsigned v = (t >= off) ? wsum[t - off] : 0u;
    __syncthreads();
    wsum[t] += v;
    __syncthreads();
  }
  unsigned excl = wsum[t] - tsum;
  unsigned c0 = excl, c1 = c0 + h0, c2 = c1 + h1, c3 = c2 + h2;
  cur[4 * t] = c0; cur[4 * t + 1] = c1; cur[4 * t + 2] = c2; cur[4 * t + 3] = c3;
  unsigned* dp = dstptr + (size_t)g * (PP + 1);
  dp[4 * t] = c0; dp[4 * t + 1] = c1; dp[4 * t + 2] = c2; dp[4 * t + 3] = c3;
  if (t == 0) dp[PP] = e1 - e0;
  __syncthreads();
  unsigned short* eg = esrc16 + (size_t)g * ECAP;
  for (unsigned e = e0 + t; e < e1; e += 256) {
    unsigned pk = epack[e];
    unsigned so = pk & 1023, dofs = (pk >> 10) & 1023;
    unsigned pos = atomicAdd(&cur[dofs], 1u);
    if (pos < ECAP) eg[pos] = (unsigned short)so;
  }
}

// ---------------- dis from CSR degrees ----------------
__global__ void k_dis(const unsigned* __restrict__ dstptr, float* __restrict__ dis) {
  int n = blockIdx.x * 256 + threadIdx.x;
  int g = n >> 10, k = n & 1023;
  const unsigned* dp = dstptr + (size_t)g * (PP + 1) + k;
  float deg = (float)(dp[1] - dp[0]);
  dis[n] = 1.0f / sqrtf(deg + 1.0f);
}

// ---------------- fp32 GEMM (layer1 only, K=128): out(N x 32) = xin @ W ----------------
// 128 rows/block, grid N/128 = 2048 -> ~7 blocks/CU resident (vs 2 before).
__global__ __launch_bounds__(256) void k_gemm(const float* __restrict__ xin, int ldx, int K,
                                              const float* __restrict__ W,
                                              float* __restrict__ out) {
  __shared__ float Wt[32 * (FIN + 4)];
  int t = threadIdx.x, b = blockIdx.x;
  int stride = K + 4;
  for (int idx = t; idx < K * 32; idx += 256) {
    int k = idx >> 5, c = idx & 31;
    Wt[c * stride + k] = W[idx];
  }
  __syncthreads();
  int cg = t & 3, ng = t >> 2;
  int row0 = b * 128 + ng * 2;
  float acc[2][8];
#pragma unroll
  for (int r = 0; r < 2; ++r)
#pragma unroll
    for (int j = 0; j < 8; ++j) acc[r][j] = 0.f;
  const float* x0 = xin + (size_t)row0 * ldx;
  const float* x1 = xin + (size_t)(row0 + 1) * ldx;
  for (int k4 = 0; k4 < (K >> 2); ++k4) {
    float4 xv0 = *(const float4*)(x0 + k4 * 4);
    float4 xv1 = *(const float4*)(x1 + k4 * 4);
    float4 wvv[8];
#pragma unroll
    for (int j = 0; j < 8; ++j)
      wvv[j] = *(const float4*)&Wt[(cg + 4 * j) * stride + k4 * 4];
#pragma unroll
    for (int j = 0; j < 8; ++j) {
      acc[0][j] += xv0.x * wvv[j].x + xv0.y * wvv[j].y + xv0.z * wvv[j].z + xv0.w * wvv[j].w;
      acc[1][j] += xv1.x * wvv[j].x + xv1.y * wvv[j].y + xv1.z * wvv[j].z + xv1.w * wvv[j].w;
    }
  }
#pragma unroll
  for (int r = 0; r < 2; ++r)
#pragma unroll
    for (int j = 0; j < 8; ++j)
      out[(size_t)(row0 + r) * HH + cg + 4 * j] = acc[r][j];
}

// ---------------- fused aggregation + tanh + next-layer 32x32 linear ----------------
// One block (512 thr) per graph, all 32 channels in LDS: hsl[1024][HSTR] fp32 = 144 KB.
// HSTR=36 -> quad-bank group of row k = k mod 8 -> random-src ds_read_b128 conflict-free.
// Each thread owns 2 dst nodes; acc in regs; writes h column block; if Wn != null also
// computes hlin_next = tanh_out @ Wn (W rows wave-uniform -> scalar loads, no LDS traffic).
__global__ __launch_bounds__(512) void k_aggf(const float* __restrict__ hlin,
                                              const float* __restrict__ dis,
                                              const unsigned short* __restrict__ esrc16,
                                              const unsigned* __restrict__ dstptr,
                                              const float* __restrict__ bias,
                                              int coloff,
                                              float* __restrict__ h,
                                              const float* __restrict__ Wn,
                                              float* __restrict__ hlin_next) {
  __shared__ float hsl[PP * HSTR];
  int t = threadIdx.x, g = blockIdx.x;
  const float4* hg = (const float4*)(hlin + (size_t)g * PP * HH);
  const float* dg = dis + (size_t)g * PP;
  for (int idx = t; idx < PP * 8; idx += 512) {
    float4 v = hg[idx];
    float d = dg[idx >> 3];
    float4 s;
    s.x = v.x * d; s.y = v.y * d; s.z = v.z * d; s.w = v.w * d;
    *(float4*)&hsl[(idx >> 3) * HSTR + (idx & 7) * 4] = s;
  }
  const unsigned* dp = dstptr + (size_t)g * (PP + 1);
  const unsigned short* eg = esrc16 + (size_t)g * ECAP;
  float4 bl[8];
#pragma unroll
  for (int j = 0; j < 8; ++j) bl[j] = ((const float4*)bias)[j];
  __syncthreads();
#pragma unroll 1
  for (int p = 0; p < 2; ++p) {
    int k = t + p * 512;
    float dk = dg[k];
    unsigned e0 = dp[k], e1 = dp[k + 1];
    float4 acc[8];
    const float* sp = &hsl[k * HSTR];
#pragma unroll
    for (int j = 0; j < 8; ++j) acc[j] = *(const float4*)(sp + 4 * j);  // self term (pre-scaled)
    unsigned e = e0;
    for (; e + 1 < e1; e += 2) {
      int s0 = eg[e], s1 = eg[e + 1];
      const float* q0 = &hsl[s0 * HSTR];
      const float* q1 = &hsl[s1 * HSTR];
#pragma unroll
      for (int j = 0; j < 8; ++j) {
        float4 a = *(const float4*)(q0 + 4 * j);
        float4 b2 = *(const float4*)(q1 + 4 * j);
        acc[j].x += a.x + b2.x; acc[j].y += a.y + b2.y;
        acc[j].z += a.z + b2.z; acc[j].w += a.w + b2.w;
      }
    }
    if (e < e1) {
      int s0 = eg[e];
      const float* q0 = &hsl[s0 * HSTR];
#pragma unroll
      for (int j = 0; j < 8; ++j) {
        float4 a = *(const float4*)(q0 + 4 * j);
        acc[j].x += a.x; acc[j].y += a.y; acc[j].z += a.z; acc[j].w += a.w;
      }
    }
    float xn[32];
#pragma unroll
    for (int j = 0; j < 8; ++j) {
      xn[4 * j + 0] = tanhf(dk * acc[j].x + bl[j].x);
      xn[4 * j + 1] = tanhf(dk * acc[j].y + bl[j].y);
      xn[4 * j + 2] = tanhf(dk * acc[j].z + bl[j].z);
      xn[4 * j + 3] = tanhf(dk * acc[j].w + bl[j].w);
    }
    float* hr = h + (size_t)(g * PP + k) * IL + coloff;
#pragma unroll
    for (int j = 0; j < 8; ++j) {
      float4 s;
      s.x = xn[4 * j]; s.y = xn[4 * j + 1]; s.z = xn[4 * j + 2]; s.w = xn[4 * j + 3];
      *(float4*)(hr + 4 * j) = s;
    }
    if (Wn) {
      float4 o4[8];
#pragma unroll
      for (int j = 0; j < 8; ++j) { o4[j].x = 0.f; o4[j].y = 0.f; o4[j].z = 0.f; o4[j].w = 0.f; }
#pragma unroll
      for (int c = 0; c < 32; ++c) {
        float xc = xn[c];
        const float4* wr = (const float4*)(Wn + c * 32);
#pragma unroll
        for (int j = 0; j < 8; ++j) {
          float4 w = wr[j];
          o4[j].x += xc * w.x; o4[j].y += xc * w.y;
          o4[j].z += xc * w.z; o4[j].w += xc * w.w;
        }
      }
      float* orow = hlin_next + (size_t)(g * PP + k) * HH;
#pragma unroll
      for (int j = 0; j < 8; ++j) *(float4*)(orow + 4 * j) = o4[j];
    }
  }
}

// ---------------- per-graph stable descending sort by last channel (bitonic) ----------------
__global__ void k_sort(const float* __restrict__ h, unsigned short* __restrict__ rank16) {
  __shared__ float key[PP];
  __shared__ unsigned sidx[PP];
  int t = threadIdx.x, g = blockIdx.x;
  for (int i = t; i < PP; i += 256) {
    key[i] = h[(size_t)(g * PP + i) * IL + (IL - 1)];
    sidx[i] = i;
  }
  __syncthreads();
  for (int sz = 2; sz <= PP; sz <<= 1) {
    for (int st = sz >> 1; st > 0; st >>= 1) {
      for (int q = t; q < PP / 2; q += 256) {
        int i = 2 * q - (q & (st - 1));
        int j = i + st;
        float ki = key[i], kj = key[j];
        unsigned ii = sidx[i], ij = sidx[j];
        bool less_ji = (kj > ki) || (kj == ki && ij < ii);
        bool asc = ((i & sz) == 0);
        if (less_ji == asc) { key[i] = kj; key[j] = ki; sidx[i] = ij; sidx[j] = ii; }
      }
      __syncthreads();
    }
  }
  for (int i = t; i < PP; i += 256) rank16[g * PP + sidx[i]] = (unsigned short)i;
}

// ---------------- position encoding ----------------
__global__ void k_pe(float* __restrict__ pe) {
  int id = blockIdx.x * 256 + threadIdx.x;
  if (id >= PP * 48) return;
  int pos = id / 48, i = id % 48;
  float denom = powf(10000.0f, (2.0f * i) / 96.0f);
  float ang = (float)pos / denom;
  pe[pos * IL + 2 * i] = sinf(ang);
  pe[pos * IL + 2 * i + 1] = cosf(ang);
}

// ---------------- WPE[c][pos][j] = sum_i capsW[c][j][i] * pe[pos][i], fp16 ----------------
__global__ void k_wpe(const float* __restrict__ pe, const float* __restrict__ capsW,
                      __half* __restrict__ wpe) {
  int id = blockIdx.x * 256 + threadIdx.x;
  if (id >= NC * PP * OL) return;
  int j = id & 15;
  int pos = (id >> 4) & 1023;
  int c = id >> 14;
  const float* wr = capsW + (size_t)(c * OL + j) * IL;
  const float* pr = pe + (size_t)pos * IL;
  float a = 0;
#pragma unroll 8
  for (int i = 0; i < IL; ++i) a += wr[i] * pr[i];
  wpe[(((size_t)c << 10) + pos) * 16 + j] = __float2half(a);
}

// ---------------- priors GEMM via MFMA f16: Pc[g][c][k][16] = h[k] @ capsW[c*16+j] ---------
__global__ __launch_bounds__(256) void k_pgemm(const float* __restrict__ h,
                                               const float* __restrict__ capsW,
                                               __half* __restrict__ Pc) {
  int t = threadIdx.x, b = blockIdx.x;
  int g = b >> 2;
  int wv = t >> 6, lane = t & 63;
  int quad = lane >> 4, l16 = lane & 15;
  half8 afr[4][3];
#pragma unroll
  for (int rt = 0; rt < 4; ++rt) {
    int row = b * 256 + wv * 64 + rt * 16 + l16;
    const float* hr = h + (size_t)row * IL + quad * 8;
#pragma unroll
    for (int kb = 0; kb < 3; ++kb) {
      float4 x = *(const float4*)(hr + kb * 32);
      float4 y = *(const float4*)(hr + kb * 32 + 4);
      half8 a;
      a[0] = (_Float16)x.x; a[1] = (_Float16)x.y; a[2] = (_Float16)x.z; a[3] = (_Float16)x.w;
      a[4] = (_Float16)y.x; a[5] = (_Float16)y.y; a[6] = (_Float16)y.z; a[7] = (_Float16)y.w;
      afr[rt][kb] = a;
    }
  }
  int krow_base = (b & 3) * 256 + wv * 64;
  for (int ct = 0; ct < NC; ++ct) {
    half8 bfr[3];
    const float* wr = capsW + (size_t)(ct * 16 + l16) * IL + quad * 8;
#pragma unroll
    for (int kb = 0; kb < 3; ++kb) {
      float4 x = *(const float4*)(wr + kb * 32);
      float4 y = *(const float4*)(wr + kb * 32 + 4);
      half8 bb;
      bb[0] = (_Float16)x.x; bb[1] = (_Float16)x.y; bb[2] = (_Float16)x.z; bb[3] = (_Float16)x.w;
      bb[4] = (_Float16)y.x; bb[5] = (_Float16)y.y; bb[6] = (_Float16)y.z; bb[7] = (_Float16)y.w;
      bfr[kb] = bb;
    }
#pragma unroll
    for (int rt = 0; rt < 4; ++rt) {
      f32x4 acc = {0.f, 0.f, 0.f, 0.f};
      acc = __builtin_amdgcn_mfma_f32_16x16x32_f16(afr[rt][0], bfr[0], acc, 0, 0, 0);
      acc = __builtin_amdgcn_mfma_f32_16x16x32_f16(afr[rt][1], bfr[1], acc, 0, 0, 0);
      acc = __builtin_amdgcn_mfma_f32_16x16x32_f16(afr[rt][2], bfr[2], acc, 0, 0, 0);
      int krow = krow_base + rt * 16;
      __half* po = Pc + ((((size_t)g * NC + ct) << 10) + krow) * 16 + l16;
#pragma unroll
      for (int r = 0; r < 4; ++r)
        po[(quad * 4 + r) * 16] = __float2half(acc[r]);
    }
  }
}

// ---------------- routing: one block per (graph, capsule), P rows in registers ----------------
__global__ __launch_bounds__(256) void k_route2(const __half* __restrict__ Pc,
                                                const __half* __restrict__ wpe,
                                                const unsigned short* __restrict__ rank16,
                                                float* __restrict__ out) {
  __shared__ float v_l[16];
  __shared__ float wred[4][17];
  int t = threadIdx.x;
  int gc = blockIdx.x;
  int g = gc / NC, c = gc - g * NC;
  int lane = t & 63, wv = t >> 6;
  const __half* pg = Pc + ((size_t)gc << 10) * 16;
  const unsigned short* rk = rank16 + (size_t)g * PP;
  const __half* wc = wpe + ((size_t)c << 10) * 16;
  float pr[4][16];
  float vsum[16];
#pragma unroll
  for (int i = 0; i < 16; ++i) vsum[i] = 0.f;
#pragma unroll
  for (int r = 0; r < 4; ++r) {
    int k = t + r * 256;
    uint4 a0 = *(const uint4*)(pg + (size_t)k * 16);
    uint4 a1 = *(const uint4*)(pg + (size_t)k * 16 + 8);
    int rkk = rk[k];
    uint4 b0 = *(const uint4*)(wc + (size_t)rkk * 16);
    uint4 b1 = *(const uint4*)(wc + (size_t)rkk * 16 + 8);
    const __half2* pa0 = (const __half2*)&a0; const __half2* pa1 = (const __half2*)&a1;
    const __half2* pb0 = (const __half2*)&b0; const __half2* pb1 = (const __half2*)&b1;
#pragma unroll
    for (int j = 0; j < 4; ++j) {
      float2 fa = __half22float2(pa0[j]); float2 fb = __half22float2(pb0[j]);
      pr[r][2 * j] = fa.x + fb.x; pr[r][2 * j + 1] = fa.y + fb.y;
      float2 fa1 = __half22float2(pa1[j]); float2 fb1 = __half22float2(pb1[j]);
      pr[r][8 + 2 * j] = fa1.x + fb1.x; pr[r][8 + 2 * j + 1] = fa1.y + fb1.y;
    }
#pragma unroll
    for (int i = 0; i < 16; ++i) vsum[i] += pr[r][i];
  }
#pragma unroll
  for (int d = 1; d < 64; d <<= 1)
#pragma unroll
    for (int i = 0; i < 16; ++i) vsum[i] += __shfl_xor(vsum[i], d, 64);
  if (lane == 0) {
#pragma unroll
    for (int i = 0; i < 16; ++i) wred[wv][i] = vsum[i];
  }
  __syncthreads();
  if (t < 16) v_l[t] = wred[0][t] + wred[1][t] + wred[2][t] + wred[3][t];
  __syncthreads();
  for (int it = 0; it < NITER; ++it) {
    float vn[16]; float n2 = 0;
#pragma unroll
    for (int i = 0; i < 16; ++i) { float x = v_l[i]; vn[i] = x; n2 += x * x; }
    float inv = 1.0f / (sqrtf(n2) + 1e-12f);
#pragma unroll
    for (int i = 0; i < 16; ++i) vn[i] *= inv;
    float lg[4];
#pragma unroll
    for (int r = 0; r < 4; ++r) {
      float a = 0;
#pragma unroll
      for (int i = 0; i < 16; ++i) a += pr[r][i] * vn[i];
      lg[r] = a;
    }
    float mx = fmaxf(fmaxf(lg[0], lg[1]), fmaxf(lg[2], lg[3]));
#pragma unroll
    for (int d = 1; d < 64; d <<= 1) mx = fmaxf(mx, __shfl_xor(mx, d, 64));
    __syncthreads();   // wred safe to rewrite
    if (lane == 0) wred[wv][16] = mx;
    __syncthreads();
    float gmax = fmaxf(fmaxf(wred[0][16], wred[1][16]), fmaxf(wred[2][16], wred[3][16]));
    float es = 0; float eacc[16];
#pragma unroll
    for (int i = 0; i < 16; ++i) eacc[i] = 0.f;
#pragma unroll
    for (int r = 0; r < 4; ++r) {
      float e = __expf(lg[r] - gmax);
      es += e;
#pragma unroll
      for (int i = 0; i < 16; ++i) eacc[i] += e * pr[r][i];
    }
#pragma unroll
    for (int d = 1; d < 64; d <<= 1) {
      es += __shfl_xor(es, d, 64);
#pragma unroll
      for (int i = 0; i < 16; ++i) eacc[i] += __shfl_xor(eacc[i], d, 64);
    }
    __syncthreads();   // gmax consumed by all waves
    if (lane == 0) {
#pragma unroll
      for (int i = 0; i < 16; ++i) wred[wv][i] = eacc[i];
      wred[wv][16] = es;
    }
    __syncthreads();
    if (t < 16) {
      float s = wred[0][t] + wred[1][t] + wred[2][t] + wred[3][t];
      float S = wred[0][16] + wred[1][16] + wred[2][16] + wred[3][16];
      v_l[t] = s / S;
    }
    __syncthreads();
  }
  if (t == 0) {
    float n2 = 0;
#pragma unroll
    for (int i = 0; i < 16; ++i) { float x = v_l[i]; n2 += x * x; }
    out[gc] = (n2 / (1.0f + n2)) * sqrtf(n2) / sqrtf(n2 + 1e-12f);
  }
}

extern "C" void kernel_launch(void* const* d_in, const int* in_sizes, int n_in,
                              void* d_out, int out_size, void* d_ws, size_t ws_size,
                              hipStream_t stream) {
  const float* x     = (const float*)d_in[0];
  const int*   ei    = (const int*)d_in[1];
  const float* W1    = (const float*)d_in[3];
  const float* b1    = (const float*)d_in[4];
  const float* W2    = (const float*)d_in[5];
  const float* b2    = (const float*)d_in[6];
  const float* W3    = (const float*)d_in[7];
  const float* b3    = (const float*)d_in[8];
  const float* capsW = (const float*)d_in[9];
  float* out = (float*)d_out;

  char* wp = (char*)d_ws;
  auto alloc = [&](size_t bytes) { char* p = wp; wp += (bytes + 255) & ~(size_t)255; return p; };
  float*    dis    = (float*)alloc((size_t)N_NODES * 4);
  float*    h      = (float*)alloc((size_t)N_NODES * IL * 4);
  // --- union region (later fully overlaid by Pc, 80 MiB) ---
  // [hlinA 32M (aliases epack 16M, dead before gemm1)] [hlinB 32M] [esrc16 9M] [histT 1M] [cbaseT 1M]
  char*     ureg   = wp;
  float*    hlinA  = (float*)alloc((size_t)N_NODES * HH * 4);            // 32 MB
  float*    hlinB  = (float*)alloc((size_t)N_NODES * HH * 4);            // 32 MB
  unsigned short* esrc16 = (unsigned short*)alloc((size_t)NG * ECAP * 2);// 9 MB
  unsigned* histT  = (unsigned*)alloc((size_t)NCHUNK * NG * 4);          // 1 MB
  unsigned* cbaseT = (unsigned*)alloc((size_t)NCHUNK * NG * 4);          // 1 MB
  unsigned* epack  = (unsigned*)hlinA;                                   // alias (dead before hlinA live)
  const size_t PC_BYTES = (size_t)NG * NC * PP * 16 * 2;                 // 80 MiB
  if ((size_t)(wp - ureg) < PC_BYTES) wp = ureg + ((PC_BYTES + 255) & ~(size_t)255);
  __half*   Pc     = (__half*)ureg;                                      // overlays union
  unsigned* gtot   = (unsigned*)alloc((size_t)NG * 4);
  unsigned* gbase  = (unsigned*)alloc((size_t)(NG + 1) * 4);
  unsigned* dstptr = (unsigned*)alloc((size_t)NG * (PP + 1) * 4);
  unsigned short* rank16 = (unsigned short*)alloc((size_t)NG * PP * 2);
  float*    pe     = (float*)alloc((size_t)PP * IL * 4);
  __half*   wpe    = (__half*)alloc((size_t)NC * PP * OL * 2);

  k_hist<<<NCHUNK, 256, 0, stream>>>(ei, histT);
  k_scanA<<<NG, 256, 0, stream>>>(histT, cbaseT, gtot);
  k_scanB<<<1, 256, 0, stream>>>(gtot, gbase);
  k_scatter<<<NCHUNK, 256, 0, stream>>>(ei, cbaseT, gbase, epack);
  k_dstsort<<<NG, 256, 0, stream>>>(epack, gbase, esrc16, dstptr);
  k_dis<<<N_NODES / 256, 256, 0, stream>>>(dstptr, dis);
  k_pe<<<(PP * 48) / 256, 256, 0, stream>>>(pe);
  k_wpe<<<(NC * PP * OL) / 256, 256, 0, stream>>>(pe, capsW, wpe);

  k_gemm<<<N_NODES / 128, 256, 0, stream>>>(x, FIN, FIN, W1, hlinA);
  k_aggf<<<NG, 512, 0, stream>>>(hlinA, dis, esrc16, dstptr, b1, 0,  h, W2, hlinB);
  k_aggf<<<NG, 512, 0, stream>>>(hlinB, dis, esrc16, dstptr, b2, 32, h, W3, hlinA);
  k_aggf<<<NG, 512, 0, stream>>>(hlinA, dis, esrc16, dstptr, b3, 64, h, nullptr, nullptr);

  k_sort<<<NG, 256, 0, stream>>>(h, rank16);
  k_pgemm<<<N_NODES / 256, 256, 0, stream>>>(h, capsW, Pc);   // Pc overlays dead buffers
  k_route2<<<NG * NC, 256, 0, stream>>>(Pc, wpe, rank16, out);
}

// Round 3
// 628.642 us; speedup vs baseline: 1.2398x; 1.0299x over previous
//
#include <hip/hip_runtime.h>
#include <hip/hip_fp16.h>
#include <cstdint>
#include <cstddef>

#define N_NODES   262144
#define NG        256
#define PP        1024
#define NE        4194304
#define FIN       128
#define HH        32
#define NC        10
#define OL        16
#define IL        96
#define NITER     3
#define ECHUNK    4096
#define NCHUNK    (NE/ECHUNK)   // 1024
#define ECAP      18432
#define HSTR      36            // 32 data cols + 4 pad cols (pads hold the 128x32 W matrix)

typedef _Float16 half8 __attribute__((ext_vector_type(8)));
typedef float f32x4 __attribute__((ext_vector_type(4)));

// ---------------- per-chunk per-graph edge histogram (transposed output) ----------------
__global__ void k_hist(const int* __restrict__ ei, unsigned* __restrict__ histT) {
  __shared__ unsigned lh[NG];
  int t = threadIdx.x, b = blockIdx.x;
  lh[t] = 0;
  __syncthreads();
  int base = b * ECHUNK;
  for (int q = t; q < ECHUNK; q += 256) {
    int e = base + q;
    int s = ei[e], d = ei[NE + e];
    if (s != d) atomicAdd(&lh[s >> 10], 1u);
  }
  __syncthreads();
  histT[t * NCHUNK + b] = lh[t];   // [g][ch]
}

// ---------------- per-graph scan over chunks: cbaseT[ch][g] (within-graph excl), gtot[g] ---
__global__ void k_scanA(const unsigned* __restrict__ histT, unsigned* __restrict__ cbaseT,
                        unsigned* __restrict__ gtot) {
  __shared__ unsigned wtot[4];
  int t = threadIdx.x, g = blockIdx.x;
  int lane = t & 63, wv = t >> 6;
  uint4 hv = *(const uint4*)(histT + (size_t)g * NCHUNK + t * 4);
  unsigned s0 = hv.x, s1 = s0 + hv.y, s2 = s1 + hv.z, s3 = s2 + hv.w;
  unsigned tsum = s3, sc = tsum;
  for (int d = 1; d < 64; d <<= 1) {
    unsigned v = __shfl_up(sc, d, 64);
    if (lane >= d) sc += v;
  }
  if (lane == 63) wtot[wv] = sc;
  __syncthreads();
  unsigned woff = 0;
  for (int w = 0; w < wv; ++w) woff += wtot[w];
  unsigned base = woff + sc - tsum;   // exclusive
  cbaseT[(size_t)(t * 4 + 0) * NG + g] = base;
  cbaseT[(size_t)(t * 4 + 1) * NG + g] = base + s0;
  cbaseT[(size_t)(t * 4 + 2) * NG + g] = base + s1;
  cbaseT[(size_t)(t * 4 + 3) * NG + g] = base + s2;
  if (t == 255) gtot[g] = woff + sc;
}

// ---------------- scan of per-graph totals -> gbase[257] ----------------
__global__ void k_scanB(const unsigned* __restrict__ gtot, unsigned* __restrict__ gbase) {
  __shared__ unsigned wtot[4];
  int t = threadIdx.x;
  int lane = t & 63, wv = t >> 6;
  unsigned x = gtot[t], sc = x;
  for (int d = 1; d < 64; d <<= 1) {
    unsigned v = __shfl_up(sc, d, 64);
    if (lane >= d) sc += v;
  }
  if (lane == 63) wtot[wv] = sc;
  __syncthreads();
  unsigned woff = 0;
  for (int w = 0; w < wv; ++w) woff += wtot[w];
  gbase[t] = woff + sc - x;
  if (t == 255) gbase[256] = woff + sc;
}

// ---------------- scatter edges into graph buckets ----------------
__global__ void k_scatter(const int* __restrict__ ei, const unsigned* __restrict__ cbaseT,
                          const unsigned* __restrict__ gbase, unsigned* __restrict__ epack) {
  __shared__ unsigned lcur[NG];
  int t = threadIdx.x, b = blockIdx.x;
  lcur[t] = gbase[t] + cbaseT[(size_t)b * NG + t];
  __syncthreads();
  int base = b * ECHUNK;
  for (int q = t; q < ECHUNK; q += 256) {
    int e = base + q;
    int s = ei[e], d = ei[NE + e];
    if (s != d) {
      int g = s >> 10;
      unsigned pos = atomicAdd(&lcur[g], 1u);
      epack[pos] = (unsigned)(s & 1023) | ((unsigned)(d & 1023) << 10);
    }
  }
}

// ---------------- per-graph counting sort by dst offset -> CSR + u16 src list ------------
__global__ __launch_bounds__(256) void k_dstsort(const unsigned* __restrict__ epack,
                          const unsigned* __restrict__ gbase,
                          unsigned short* __restrict__ esrc16,
                          unsigned* __restrict__ dstptr) {
  __shared__ unsigned shist[PP];
  __shared__ unsigned wsum[256];
  __shared__ unsigned cur[PP];
  int t = threadIdx.x, g = blockIdx.x;
  unsigned e0 = gbase[g], e1 = gbase[g + 1];
  for (int i = t; i < PP; i += 256) shist[i] = 0;
  __syncthreads();
  for (unsigned e = e0 + t; e < e1; e += 256)
    atomicAdd(&shist[(epack[e] >> 10) & 1023], 1u);
  __syncthreads();
  unsigned h0 = shist[4 * t], h1 = shist[4 * t + 1], h2 = shist[4 * t + 2], h3 = shist[4 * t + 3];
  unsigned tsum = h0 + h1 + h2 + h3;
  wsum[t] = tsum;
  __syncthreads();
  for (int off = 1; off < 256; off <<= 1) {
    unsigned v = (t >= off) ? wsum[t - off] : 0u;
    __syncthreads();
    wsum[t] += v;
    __syncthreads();
  }
  unsigned excl = wsum[t] - tsum;
  unsigned c0 = excl, c1 = c0 + h0, c2 = c1 + h1, c3 = c2 + h2;
  cur[4 * t] = c0; cur[4 * t + 1] = c1; cur[4 * t + 2] = c2; cur[4 * t + 3] = c3;
  unsigned* dp = dstptr + (size_t)g * (PP + 1);
  dp[4 * t] = c0; dp[4 * t + 1] = c1; dp[4 * t + 2] = c2; dp[4 * t + 3] = c3;
  if (t == 0) dp[PP] = e1 - e0;
  __syncthreads();
  unsigned short* eg = esrc16 + (size_t)g * ECAP;
  for (unsigned e = e0 + t; e < e1; e += 256) {
    unsigned pk = epack[e];
    unsigned so = pk & 1023, dofs = (pk >> 10) & 1023;
    unsigned pos = atomicAdd(&cur[dofs], 1u);
    if (pos < ECAP) eg[pos] = (unsigned short)so;
  }
}

// ---------------- dis from CSR degrees ----------------
__global__ void k_dis(const unsigned* __restrict__ dstptr, float* __restrict__ dis) {
  int n = blockIdx.x * 256 + threadIdx.x;
  int g = n >> 10, k = n & 1023;
  const unsigned* dp = dstptr + (size_t)g * (PP + 1) + k;
  float deg = (float)(dp[1] - dp[0]);
  dis[n] = 1.0f / sqrtf(deg + 1.0f);
}

// ---------------- one GCN layer: gather from hsl -> tanh -> h cols; optional in-thread
// 32x32 linear with W from pads -> overwrite hsl with hlin_next * d ----------------
__device__ __forceinline__ void gcn_layer(float* hsl, const float* dg, const unsigned* dp,
                                          const unsigned short* eg, const float* bias,
                                          int coloff, const float* Wn, float* hbase, int t) {
  float4 bl[8];
#pragma unroll
  for (int j = 0; j < 8; ++j) bl[j] = ((const float4*)bias)[j];
  // stage next-layer W into the pad columns (previous pad content is dead here);
  // concurrent with gather below (pads are disjoint from data cols 0..31).
  if (Wn) {
#pragma unroll
    for (int pp = 0; pp < 8; ++pp) {
      int p = t + pp * 512;
      hsl[(p >> 2) * HSTR + 32 + (p & 3)] = Wn[p];
    }
  }
  float xn[2][32];
#pragma unroll
  for (int pth = 0; pth < 2; ++pth) {
    int k = t + pth * 512;
    float dk = dg[k];
    unsigned e0 = dp[k], e1 = dp[k + 1];
    if (e1 > (unsigned)ECAP) e1 = ECAP;   // defensive: eg region is ECAP entries
    float4 acc[8];
    const float* sp = &hsl[k * HSTR];
#pragma unroll
    for (int j = 0; j < 8; ++j) acc[j] = *(const float4*)(sp + 4 * j);  // self (pre-scaled)
    unsigned e = e0;
    for (; e + 1 < e1; e += 2) {
      int s0 = eg[e], s1 = eg[e + 1];
      const float* q0 = &hsl[s0 * HSTR];
      const float* q1 = &hsl[s1 * HSTR];
#pragma unroll
      for (int j = 0; j < 8; ++j) {
        float4 a = *(const float4*)(q0 + 4 * j);
        float4 b2 = *(const float4*)(q1 + 4 * j);
        acc[j].x += a.x + b2.x; acc[j].y += a.y + b2.y;
        acc[j].z += a.z + b2.z; acc[j].w += a.w + b2.w;
      }
    }
    if (e < e1) {
      int s0 = eg[e];
      const float* q0 = &hsl[s0 * HSTR];
#pragma unroll
      for (int j = 0; j < 8; ++j) {
        float4 a = *(const float4*)(q0 + 4 * j);
        acc[j].x += a.x; acc[j].y += a.y; acc[j].z += a.z; acc[j].w += a.w;
      }
    }
#pragma unroll
    for (int j = 0; j < 8; ++j) {
      xn[pth][4 * j + 0] = tanhf(dk * acc[j].x + bl[j].x);
      xn[pth][4 * j + 1] = tanhf(dk * acc[j].y + bl[j].y);
      xn[pth][4 * j + 2] = tanhf(dk * acc[j].z + bl[j].z);
      xn[pth][4 * j + 3] = tanhf(dk * acc[j].w + bl[j].w);
    }
    float* hr = hbase + (size_t)k * IL + coloff;
#pragma unroll
    for (int j = 0; j < 8; ++j) {
      float4 s;
      s.x = xn[pth][4 * j]; s.y = xn[pth][4 * j + 1];
      s.z = xn[pth][4 * j + 2]; s.w = xn[pth][4 * j + 3];
      *(float4*)(hr + 4 * j) = s;
    }
  }
  __syncthreads();   // all hsl reads done; W pads written
  if (Wn) {
#pragma unroll
    for (int pth = 0; pth < 2; ++pth) {
      int k = t + pth * 512;
      float dk = dg[k];
      float4 o4[8];
#pragma unroll
      for (int j = 0; j < 8; ++j) { o4[j].x = 0.f; o4[j].y = 0.f; o4[j].z = 0.f; o4[j].w = 0.f; }
#pragma unroll
      for (int c = 0; c < 32; ++c) {
        float xc = xn[pth][c];
#pragma unroll
        for (int j4 = 0; j4 < 8; ++j4) {
          float4 w = *(const float4*)&hsl[(c * 8 + j4) * HSTR + 32];   // broadcast
          o4[j4].x += xc * w.x; o4[j4].y += xc * w.y;
          o4[j4].z += xc * w.z; o4[j4].w += xc * w.w;
        }
      }
      float* op = &hsl[k * HSTR];
#pragma unroll
      for (int j4 = 0; j4 < 8; ++j4) {
        float4 s;
        s.x = o4[j4].x * dk; s.y = o4[j4].y * dk;
        s.z = o4[j4].z * dk; s.w = o4[j4].w * dk;
        *(float4*)(op + 4 * j4) = s;
      }
    }
    __syncthreads();   // hsl now holds hlin_next * d
  }
}

// ---------------- whole 3-layer GCN: one block per graph, hlin never leaves LDS ----------
__global__ __launch_bounds__(512) void k_gcn(const float* __restrict__ x,
                                             const float* __restrict__ dis,
                                             const unsigned short* __restrict__ esrc16,
                                             const unsigned* __restrict__ dstptr,
                                             const float* __restrict__ W1, const float* __restrict__ b1,
                                             const float* __restrict__ W2, const float* __restrict__ b2,
                                             const float* __restrict__ W3, const float* __restrict__ b3,
                                             float* __restrict__ h) {
  __shared__ float hsl[PP * HSTR];   // 144 KB: [1024 rows][32 data + 4 pad]
  int t = threadIdx.x, g = blockIdx.x;
  const float* dg = dis + (size_t)g * PP;
  const unsigned* dp = dstptr + (size_t)g * (PP + 1);
  const unsigned short* eg = esrc16 + (size_t)g * ECAP;
  float* hbase = h + (size_t)g * PP * IL;

  // pads <- W1 (128x32 = 4096 floats == exactly the pad capacity)
#pragma unroll
  for (int pp = 0; pp < 8; ++pp) {
    int p = t + pp * 512;
    hsl[(p >> 2) * HSTR + 32 + (p & 3)] = W1[p];
  }
  __syncthreads();

  // GEMM1: hsl[row][0..31] = (x_row @ W1) * d_row.  8 rows x 8 cols per thread.
  {
    int cg = t & 3, ng = t >> 2;          // ng 0..127
    int row0 = ng * 8;
    const float* xr = x + ((size_t)g * PP + row0) * FIN;
    float acc[8][8];
#pragma unroll
    for (int r = 0; r < 8; ++r)
#pragma unroll
      for (int j = 0; j < 8; ++j) acc[r][j] = 0.f;
    for (int k4 = 0; k4 < FIN / 4; ++k4) {
      float4 xv[8];
#pragma unroll
      for (int r = 0; r < 8; ++r)
        xv[r] = *(const float4*)(xr + (size_t)r * FIN + k4 * 4);
#pragma unroll
      for (int kk = 0; kk < 4; ++kk) {
        int k = k4 * 4 + kk;
        float4 wa = *(const float4*)&hsl[(k * 8 + cg * 2) * HSTR + 32];
        float4 wb = *(const float4*)&hsl[(k * 8 + cg * 2 + 1) * HSTR + 32];
#pragma unroll
        for (int r = 0; r < 8; ++r) {
          float xk = kk == 0 ? xv[r].x : kk == 1 ? xv[r].y : kk == 2 ? xv[r].z : xv[r].w;
          acc[r][0] += xk * wa.x; acc[r][1] += xk * wa.y;
          acc[r][2] += xk * wa.z; acc[r][3] += xk * wa.w;
          acc[r][4] += xk * wb.x; acc[r][5] += xk * wb.y;
          acc[r][6] += xk * wb.z; acc[r][7] += xk * wb.w;
        }
      }
    }
#pragma unroll
    for (int r = 0; r < 8; ++r) {
      float d = dg[row0 + r];
      float4 s0, s1;
      s0.x = acc[r][0] * d; s0.y = acc[r][1] * d; s0.z = acc[r][2] * d; s0.w = acc[r][3] * d;
      s1.x = acc[r][4] * d; s1.y = acc[r][5] * d; s1.z = acc[r][6] * d; s1.w = acc[r][7] * d;
      *(float4*)&hsl[(row0 + r) * HSTR + cg * 8] = s0;
      *(float4*)&hsl[(row0 + r) * HSTR + cg * 8 + 4] = s1;
    }
  }
  __syncthreads();

  gcn_layer(hsl, dg, dp, eg, b1, 0,  W2, hbase, t);
  gcn_layer(hsl, dg, dp, eg, b2, 32, W3, hbase, t);
  gcn_layer(hsl, dg, dp, eg, b3, 64, nullptr, hbase, t);
}

// ---------------- per-graph stable descending sort by last channel (bitonic, 512 thr) -----
__global__ __launch_bounds__(512) void k_sort(const float* __restrict__ h,
                                              unsigned short* __restrict__ rank16) {
  __shared__ float key[PP];
  __shared__ unsigned sidx[PP];
  int t = threadIdx.x, g = blockIdx.x;
  for (int i = t; i < PP; i += 512) {
    key[i] = h[(size_t)(g * PP + i) * IL + (IL - 1)];
    sidx[i] = i;
  }
  __syncthreads();
  for (int sz = 2; sz <= PP; sz <<= 1) {
    for (int st = sz >> 1; st > 0; st >>= 1) {
      int i = 2 * t - (t & (st - 1));
      int j = i + st;
      float ki = key[i], kj = key[j];
      unsigned ii = sidx[i], ij = sidx[j];
      bool less_ji = (kj > ki) || (kj == ki && ij < ii);
      bool asc = ((i & sz) == 0);
      if (less_ji == asc) { key[i] = kj; key[j] = ki; sidx[i] = ij; sidx[j] = ii; }
      __syncthreads();
    }
  }
  for (int i = t; i < PP; i += 512) rank16[g * PP + sidx[i]] = (unsigned short)i;
}

// ---------------- position encoding ----------------
__global__ void k_pe(float* __restrict__ pe) {
  int id = blockIdx.x * 256 + threadIdx.x;
  if (id >= PP * 48) return;
  int pos = id / 48, i = id % 48;
  float denom = powf(10000.0f, (2.0f * i) / 96.0f);
  float ang = (float)pos / denom;
  pe[pos * IL + 2 * i] = sinf(ang);
  pe[pos * IL + 2 * i + 1] = cosf(ang);
}

// ---------------- WPE[c][pos][j] = sum_i capsW[c][j][i] * pe[pos][i], fp16 ----------------
__global__ void k_wpe(const float* __restrict__ pe, const float* __restrict__ capsW,
                      __half* __restrict__ wpe) {
  int id = blockIdx.x * 256 + threadIdx.x;
  if (id >= NC * PP * OL) return;
  int j = id & 15;
  int pos = (id >> 4) & 1023;
  int c = id >> 14;
  const float* wr = capsW + (size_t)(c * OL + j) * IL;
  const float* pr = pe + (size_t)pos * IL;
  float a = 0;
#pragma unroll 8
  for (int i = 0; i < IL; ++i) a += wr[i] * pr[i];
  wpe[(((size_t)c << 10) + pos) * 16 + j] = __float2half(a);
}

// ---------------- priors GEMM via MFMA f16: Pc[g][c][k][16] = h[k] @ capsW[c*16+j] ---------
__global__ __launch_bounds__(256) void k_pgemm(const float* __restrict__ h,
                                               const float* __restrict__ capsW,
                                               __half* __restrict__ Pc) {
  int t = threadIdx.x, b = blockIdx.x;
  int g = b >> 2;
  int wv = t >> 6, lane = t & 63;
  int quad = lane >> 4, l16 = lane & 15;
  half8 afr[4][3];
#pragma unroll
  for (int rt = 0; rt < 4; ++rt) {
    int row = b * 256 + wv * 64 + rt * 16 + l16;
    const float* hr = h + (size_t)row * IL + quad * 8;
#pragma unroll
    for (int kb = 0; kb < 3; ++kb) {
      float4 x = *(const float4*)(hr + kb * 32);
      float4 y = *(const float4*)(hr + kb * 32 + 4);
      half8 a;
      a[0] = (_Float16)x.x; a[1] = (_Float16)x.y; a[2] = (_Float16)x.z; a[3] = (_Float16)x.w;
      a[4] = (_Float16)y.x; a[5] = (_Float16)y.y; a[6] = (_Float16)y.z; a[7] = (_Float16)y.w;
      afr[rt][kb] = a;
    }
  }
  int krow_base = (b & 3) * 256 + wv * 64;
  for (int ct = 0; ct < NC; ++ct) {
    half8 bfr[3];
    const float* wr = capsW + (size_t)(ct * 16 + l16) * IL + quad * 8;
#pragma unroll
    for (int kb = 0; kb < 3; ++kb) {
      float4 x = *(const float4*)(wr + kb * 32);
      float4 y = *(const float4*)(wr + kb * 32 + 4);
      half8 bb;
      bb[0] = (_Float16)x.x; bb[1] = (_Float16)x.y; bb[2] = (_Float16)x.z; bb[3] = (_Float16)x.w;
      bb[4] = (_Float16)y.x; bb[5] = (_Float16)y.y; bb[6] = (_Float16)y.z; bb[7] = (_Float16)y.w;
      bfr[kb] = bb;
    }
#pragma unroll
    for (int rt = 0; rt < 4; ++rt) {
      f32x4 acc = {0.f, 0.f, 0.f, 0.f};
      acc = __builtin_amdgcn_mfma_f32_16x16x32_f16(afr[rt][0], bfr[0], acc, 0, 0, 0);
      acc = __builtin_amdgcn_mfma_f32_16x16x32_f16(afr[rt][1], bfr[1], acc, 0, 0, 0);
      acc = __builtin_amdgcn_mfma_f32_16x16x32_f16(afr[rt][2], bfr[2], acc, 0, 0, 0);
      int krow = krow_base + rt * 16;
      __half* po = Pc + ((((size_t)g * NC + ct) << 10) + krow) * 16 + l16;
#pragma unroll
      for (int r = 0; r < 4; ++r)
        po[(quad * 4 + r) * 16] = __float2half(acc[r]);
    }
  }
}

// ---------------- routing: one block per (graph, capsule), P rows in registers ----------------
__global__ __launch_bounds__(256) void k_route2(const __half* __restrict__ Pc,
                                                const __half* __restrict__ wpe,
                                                const unsigned short* __restrict__ rank16,
                                                float* __restrict__ out) {
  __shared__ float v_l[16];
  __shared__ float wred[4][17];
  int t = threadIdx.x;
  int gc = blockIdx.x;
  int g = gc / NC, c = gc - g * NC;
  int lane = t & 63, wv = t >> 6;
  const __half* pg = Pc + ((size_t)gc << 10) * 16;
  const unsigned short* rk = rank16 + (size_t)g * PP;
  const __half* wc = wpe + ((size_t)c << 10) * 16;
  float pr[4][16];
  float vsum[16];
#pragma unroll
  for (int i = 0; i < 16; ++i) vsum[i] = 0.f;
#pragma unroll
  for (int r = 0; r < 4; ++r) {
    int k = t + r * 256;
    uint4 a0 = *(const uint4*)(pg + (size_t)k * 16);
    uint4 a1 = *(const uint4*)(pg + (size_t)k * 16 + 8);
    int rkk = rk[k];
    uint4 b0 = *(const uint4*)(wc + (size_t)rkk * 16);
    uint4 b1 = *(const uint4*)(wc + (size_t)rkk * 16 + 8);
    const __half2* pa0 = (const __half2*)&a0; const __half2* pa1 = (const __half2*)&a1;
    const __half2* pb0 = (const __half2*)&b0; const __half2* pb1 = (const __half2*)&b1;
#pragma unroll
    for (int j = 0; j < 4; ++j) {
      float2 fa = __half22float2(pa0[j]); float2 fb = __half22float2(pb0[j]);
      pr[r][2 * j] = fa.x + fb.x; pr[r][2 * j + 1] = fa.y + fb.y;
      float2 fa1 = __half22float2(pa1[j]); float2 fb1 = __half22float2(pb1[j]);
      pr[r][8 + 2 * j] = fa1.x + fb1.x; pr[r][8 + 2 * j + 1] = fa1.y + fb1.y;
    }
#pragma unroll
    for (int i = 0; i < 16; ++i) vsum[i] += pr[r][i];
  }
#pragma unroll
  for (int d = 1; d < 64; d <<= 1)
#pragma unroll
    for (int i = 0; i < 16; ++i) vsum[i] += __shfl_xor(vsum[i], d, 64);
  if (lane == 0) {
#pragma unroll
    for (int i = 0; i < 16; ++i) wred[wv][i] = vsum[i];
  }
  __syncthreads();
  if (t < 16) v_l[t] = wred[0][t] + wred[1][t] + wred[2][t] + wred[3][t];
  __syncthreads();
  for (int it = 0; it < NITER; ++it) {
    float vn[16]; float n2 = 0;
#pragma unroll
    for (int i = 0; i < 16; ++i) { float x = v_l[i]; vn[i] = x; n2 += x * x; }
    float inv = 1.0f / (sqrtf(n2) + 1e-12f);
#pragma unroll
    for (int i = 0; i < 16; ++i) vn[i] *= inv;
    float lg[4];
#pragma unroll
    for (int r = 0; r < 4; ++r) {
      float a = 0;
#pragma unroll
      for (int i = 0; i < 16; ++i) a += pr[r][i] * vn[i];
      lg[r] = a;
    }
    float mx = fmaxf(fmaxf(lg[0], lg[1]), fmaxf(lg[2], lg[3]));
#pragma unroll
    for (int d = 1; d < 64; d <<= 1) mx = fmaxf(mx, __shfl_xor(mx, d, 64));
    __syncthreads();   // wred safe to rewrite
    if (lane == 0) wred[wv][16] = mx;
    __syncthreads();
    float gmax = fmaxf(fmaxf(wred[0][16], wred[1][16]), fmaxf(wred[2][16], wred[3][16]));
    float es = 0; float eacc[16];
#pragma unroll
    for (int i = 0; i < 16; ++i) eacc[i] = 0.f;
#pragma unroll
    for (int r = 0; r < 4; ++r) {
      float e = __expf(lg[r] - gmax);
      es += e;
#pragma unroll
      for (int i = 0; i < 16; ++i) eacc[i] += e * pr[r][i];
    }
#pragma unroll
    for (int d = 1; d < 64; d <<= 1) {
      es += __shfl_xor(es, d, 64);
#pragma unroll
      for (int i = 0; i < 16; ++i) eacc[i] += __shfl_xor(eacc[i], d, 64);
    }
    __syncthreads();   // gmax consumed by all waves
    if (lane == 0) {
#pragma unroll
      for (int i = 0; i < 16; ++i) wred[wv][i] = eacc[i];
      wred[wv][16] = es;
    }
    __syncthreads();
    if (t < 16) {
      float s = wred[0][t] + wred[1][t] + wred[2][t] + wred[3][t];
      float S = wred[0][16] + wred[1][16] + wred[2][16] + wred[3][16];
      v_l[t] = s / S;
    }
    __syncthreads();
  }
  if (t == 0) {
    float n2 = 0;
#pragma unroll
    for (int i = 0; i < 16; ++i) { float x = v_l[i]; n2 += x * x; }
    out[gc] = (n2 / (1.0f + n2)) * sqrtf(n2) / sqrtf(n2 + 1e-12f);
  }
}

extern "C" void kernel_launch(void* const* d_in, const int* in_sizes, int n_in,
                              void* d_out, int out_size, void* d_ws, size_t ws_size,
                              hipStream_t stream) {
  const float* x     = (const float*)d_in[0];
  const int*   ei    = (const int*)d_in[1];
  const float* W1    = (const float*)d_in[3];
  const float* b1    = (const float*)d_in[4];
  const float* W2    = (const float*)d_in[5];
  const float* b2    = (const float*)d_in[6];
  const float* W3    = (const float*)d_in[7];
  const float* b3    = (const float*)d_in[8];
  const float* capsW = (const float*)d_in[9];
  float* out = (float*)d_out;

  char* wp = (char*)d_ws;
  auto alloc = [&](size_t bytes) { char* p = wp; wp += (bytes + 255) & ~(size_t)255; return p; };
  float*    dis    = (float*)alloc((size_t)N_NODES * 4);
  float*    h      = (float*)alloc((size_t)N_NODES * IL * 4);
  // --- union region (later fully overlaid by Pc, 80 MiB):
  // [epack 16M] [esrc16 9M] [histT 1M] [cbaseT 1M] — all dead before Pc is written
  char*     ureg   = wp;
  unsigned* epack  = (unsigned*)alloc((size_t)NE * 4);                   // 16 MB
  unsigned short* esrc16 = (unsigned short*)alloc((size_t)NG * ECAP * 2);// 9 MB
  unsigned* histT  = (unsigned*)alloc((size_t)NCHUNK * NG * 4);          // 1 MB
  unsigned* cbaseT = (unsigned*)alloc((size_t)NCHUNK * NG * 4);          // 1 MB
  const size_t PC_BYTES = (size_t)NG * NC * PP * 16 * 2;                 // 80 MiB
  if ((size_t)(wp - ureg) < PC_BYTES) wp = ureg + ((PC_BYTES + 255) & ~(size_t)255);
  __half*   Pc     = (__half*)ureg;                                      // overlays union
  unsigned* gtot   = (unsigned*)alloc((size_t)NG * 4);
  unsigned* gbase  = (unsigned*)alloc((size_t)(NG + 1) * 4);
  unsigned* dstptr = (unsigned*)alloc((size_t)NG * (PP + 1) * 4);
  unsigned short* rank16 = (unsigned short*)alloc((size_t)NG * PP * 2);
  float*    pe     = (float*)alloc((size_t)PP * IL * 4);
  __half*   wpe    = (__half*)alloc((size_t)NC * PP * OL * 2);

  k_hist<<<NCHUNK, 256, 0, stream>>>(ei, histT);
  k_scanA<<<NG, 256, 0, stream>>>(histT, cbaseT, gtot);
  k_scanB<<<1, 256, 0, stream>>>(gtot, gbase);
  k_scatter<<<NCHUNK, 256, 0, stream>>>(ei, cbaseT, gbase, epack);
  k_dstsort<<<NG, 256, 0, stream>>>(epack, gbase, esrc16, dstptr);
  k_dis<<<N_NODES / 256, 256, 0, stream>>>(dstptr, dis);
  k_pe<<<(PP * 48) / 256, 256, 0, stream>>>(pe);
  k_wpe<<<(NC * PP * OL) / 256, 256, 0, stream>>>(pe, capsW, wpe);

  k_gcn<<<NG, 512, 0, stream>>>(x, dis, esrc16, dstptr, W1, b1, W2, b2, W3, b3, h);

  k_sort<<<NG, 512, 0, stream>>>(h, rank16);
  k_pgemm<<<N_NODES / 256, 256, 0, stream>>>(h, capsW, Pc);   // Pc overlays dead buffers
  k_route2<<<NG * NC, 256, 0, stream>>>(Pc, wpe, rank16, out);
}